// Round 3
// baseline (2188.002 us; speedup 1.0000x reference)
//
#include <hip/hip_runtime.h>
#include <hip/hip_bf16.h>

#define LEAKY 0.2f

// Monotone float->uint encoding: enc(a) < enc(b) <=> a < b (non-NaN floats).
// Segment-max becomes a single atomicMax(unsigned) with init 0.
__device__ inline unsigned fenc(float f) {
    unsigned u = __float_as_uint(f);
    return (u & 0x80000000u) ? ~u : (u | 0x80000000u);
}
__device__ inline float fdec(unsigned u) {
    return __uint_as_float((u & 0x80000000u) ? (u ^ 0x80000000u) : ~u);
}

// ---------------- init / elementwise ----------------

__global__ void k_init_ms(unsigned* __restrict__ menc, float* __restrict__ s, int n) {
    int i = blockIdx.x * blockDim.x + threadIdx.x;
    if (i < n) { menc[i] = 0u; s[i] = 0.0f; }
}

__global__ void k_init_rst(float* __restrict__ rst, const float* __restrict__ b,
                           int total, int M) {
    int i = blockIdx.x * blockDim.x + threadIdx.x;
    if (i < total) rst[i] = b[i % M];
}

__global__ void k_relu(float* __restrict__ x, int n) {
    int i = blockIdx.x * blockDim.x + threadIdx.x;
    if (i < n) x[i] = fmaxf(x[i], 0.0f);
}

// ---------------- GEMM: C[N,M] = A[N,K] * B[K,M], all f32 ----------------
// 64x64 tile per 256-thread block, K-tile 16, 4x4 micro-tile per thread.

__global__ __launch_bounds__(256)
void k_gemm(const float* __restrict__ A, const float* __restrict__ B,
            float* __restrict__ C, int N, int K, int M) {
    __shared__ float As[64][17];
    __shared__ float Bs[16][65];
    const int tid = threadIdx.x;
    const int tx = tid & 15, ty = tid >> 4;
    const int row0 = blockIdx.y * 64;
    const int col0 = blockIdx.x * 64;

    const int ar = (tid * 4) >> 4;   // 0..63
    const int ac = (tid * 4) & 15;   // 0,4,8,12
    const int br = (tid * 4) >> 6;   // 0..15
    const int bc = (tid * 4) & 63;

    float acc[4][4] = {};

    for (int k0 = 0; k0 < K; k0 += 16) {
        float4 av = make_float4(0.f, 0.f, 0.f, 0.f);
        int gr = row0 + ar;
        if (gr < N) av = *(const float4*)(A + (size_t)gr * K + k0 + ac);
        As[ar][ac]     = av.x;
        As[ar][ac + 1] = av.y;
        As[ar][ac + 2] = av.z;
        As[ar][ac + 3] = av.w;

        float4 bv = *(const float4*)(B + (size_t)(k0 + br) * M + col0 + bc);
        Bs[br][bc]     = bv.x;
        Bs[br][bc + 1] = bv.y;
        Bs[br][bc + 2] = bv.z;
        Bs[br][bc + 3] = bv.w;
        __syncthreads();

        #pragma unroll
        for (int kk = 0; kk < 16; ++kk) {
            float a[4], b[4];
            #pragma unroll
            for (int i = 0; i < 4; ++i) a[i] = As[ty * 4 + i][kk];
            #pragma unroll
            for (int j = 0; j < 4; ++j) b[j] = Bs[kk][tx * 4 + j];
            #pragma unroll
            for (int i = 0; i < 4; ++i)
                #pragma unroll
                for (int j = 0; j < 4; ++j)
                    acc[i][j] += a[i] * b[j];
        }
        __syncthreads();
    }

    #pragma unroll
    for (int i = 0; i < 4; ++i) {
        int r = row0 + ty * 4 + i;
        if (r < N) {
            #pragma unroll
            for (int j = 0; j < 4; ++j)
                C[(size_t)r * M + col0 + tx * 4 + j] = acc[i][j];
        }
    }
}

// ---------------- attention pieces ----------------

__global__ void k_el_er(const float* __restrict__ feat, const float* __restrict__ al,
                        const float* __restrict__ ar, float* __restrict__ el,
                        float* __restrict__ er, int N, int H) {
    int idx = blockIdx.x * blockDim.x + threadIdx.x;
    if (idx >= N * H) return;
    int h = idx % H;
    int n = idx / H;
    const float* f = feat + (size_t)n * (H * 64) + h * 64;
    float sl = 0.f, sr = 0.f;
    #pragma unroll 8
    for (int d = 0; d < 64; ++d) {
        float v = f[d];
        sl += v * al[h * 64 + d];
        sr += v * ar[h * 64 + d];
    }
    el[idx] = sl;
    er[idx] = sr;
}

__global__ void k_edge_max(const int* __restrict__ src, const int* __restrict__ dst,
                           const float* __restrict__ el, const float* __restrict__ er,
                           float* __restrict__ logits, unsigned* __restrict__ menc,
                           int EH, int H, int N) {
    int idx = blockIdx.x * blockDim.x + threadIdx.x;
    if (idx >= EH) return;
    int e = idx / H;
    int h = idx - e * H;
    int sn = src[e], dn = dst[e];
    if ((unsigned)sn >= (unsigned)N || (unsigned)dn >= (unsigned)N) return;
    float x = el[sn * H + h] + er[dn * H + h];
    x = (x > 0.f) ? x : LEAKY * x;
    logits[idx] = x;
    atomicMax(&menc[dn * H + h], fenc(x));
}

__global__ void k_edge_exp(const int* __restrict__ dst, const unsigned* __restrict__ menc,
                           float* __restrict__ logits_ex, float* __restrict__ s,
                           int EH, int H, int N) {
    int idx = blockIdx.x * blockDim.x + threadIdx.x;
    if (idx >= EH) return;
    int e = idx / H;
    int h = idx - e * H;
    int dn = dst[e];
    if ((unsigned)dn >= (unsigned)N) return;
    float m = fdec(menc[dn * H + h]);
    float ex = expf(fminf(logits_ex[idx] - m, 0.0f));  // clamp: overflow impossible
    logits_ex[idx] = ex;
    atomicAdd(&s[dn * H + h], ex);
}

// one 64-lane group per edge; lane = feature d, loop over heads
__global__ __launch_bounds__(256)
void k_aggregate(const int* __restrict__ src, const int* __restrict__ dst,
                 const float* __restrict__ feat, const float* __restrict__ ex,
                 const float* __restrict__ s, float* __restrict__ rst, int E, int H, int N) {
    int e = blockIdx.x * 4 + (threadIdx.x >> 6);
    int lane = threadIdx.x & 63;
    if (e >= E) return;
    int sn = src[e], dn = dst[e];
    if ((unsigned)sn >= (unsigned)N || (unsigned)dn >= (unsigned)N) return;
    int M = H * 64;
    for (int h = 0; h < H; ++h) {
        float denom = s[dn * H + h];
        float a = ex[e * H + h] / fmaxf(denom, 1e-30f);  // 0/0 -> 0, never NaN
        float v = feat[(size_t)sn * M + h * 64 + lane] * a;
        atomicAdd(&rst[(size_t)dn * M + h * 64 + lane], v);
    }
}

// ---------------- host side ----------------

static void run_layer(const float* A, int K, const float* W,
                      const float* al_, const float* ar_, const float* b_, int H,
                      float* feat, float* rstOut,
                      float* el, float* er, unsigned* menc, float* sbuf, float* ex,
                      const int* src, const int* dst, int N, int E, bool do_relu,
                      hipStream_t stream) {
    const int M = H * 64;
    dim3 gg(M / 64, (N + 63) / 64);
    k_gemm<<<gg, 256, 0, stream>>>(A, W, feat, N, K, M);

    int nh = N * H;
    k_el_er<<<(nh + 255) / 256, 256, 0, stream>>>(feat, al_, ar_, el, er, N, H);
    k_init_ms<<<(nh + 255) / 256, 256, 0, stream>>>(menc, sbuf, nh);

    int eh = E * H;
    k_edge_max<<<(eh + 255) / 256, 256, 0, stream>>>(src, dst, el, er, ex, menc, eh, H, N);
    k_edge_exp<<<(eh + 255) / 256, 256, 0, stream>>>(dst, menc, ex, sbuf, eh, H, N);

    int nm = N * M;
    k_init_rst<<<(nm + 255) / 256, 256, 0, stream>>>(rstOut, b_, nm, M);
    k_aggregate<<<(E + 3) / 4, 256, 0, stream>>>(src, dst, feat, ex, sbuf, rstOut, E, H, N);
    if (do_relu) k_relu<<<(nm + 255) / 256, 256, 0, stream>>>(rstOut, nm);
}

extern "C" void kernel_launch(void* const* d_in, const int* in_sizes, int n_in,
                              void* d_out, int out_size, void* d_ws, size_t ws_size,
                              hipStream_t stream) {
    const float* features = (const float*)d_in[0];
    const int*   src = (const int*)d_in[1];
    const int*   dst = (const int*)d_in[2];
    const float* W1  = (const float*)d_in[3];
    const float* al1 = (const float*)d_in[4];
    const float* ar1 = (const float*)d_in[5];
    const float* b1  = (const float*)d_in[6];
    const float* W2  = (const float*)d_in[7];
    const float* al2 = (const float*)d_in[8];
    const float* ar2 = (const float*)d_in[9];
    const float* b2  = (const float*)d_in[10];
    const float* W3  = (const float*)d_in[11];
    const float* al3 = (const float*)d_in[12];
    const float* ar3 = (const float*)d_in[13];
    const float* b3  = (const float*)d_in[14];

    const int N = in_sizes[0] / 128;   // 50000
    const int E = in_sizes[1];         // 800000

    float* ws   = (float*)d_ws;
    size_t n256 = (size_t)N * 256;
    float* bufA = ws;                       // [N,256] f32
    float* bufB = bufA + n256;              // [N,256] f32
    float* el   = bufB + n256;              // [N,4]
    float* er   = el + (size_t)N * 4;
    unsigned* menc = (unsigned*)(er + (size_t)N * 4);  // [N,4]
    float* sb   = (float*)(menc + (size_t)N * 4);      // [N,4]
    float* ex   = sb + (size_t)N * 4;       // [E,4]

    // layer 1: A=features[N,128] -> feat=bufB[N,256] -> rst=bufA[N,256] (+relu)
    run_layer(features, 128, W1, al1, ar1, b1, 4, bufB, bufA,
              el, er, menc, sb, ex, src, dst, N, E, true, stream);
    // layer 2: A=bufA[N,256] -> feat=bufB[N,256] -> rst=bufA[N,256] (+relu)
    run_layer(bufA, 256, W2, al2, ar2, b2, 4, bufB, bufA,
              el, er, menc, sb, ex, src, dst, N, E, true, stream);
    // layer 3: A=bufA[N,256] -> feat=bufB[N,64] -> rst=d_out[N,64] (no relu)
    // mean over H=1 heads is identity, so write the result straight to d_out.
    run_layer(bufA, 256, W3, al3, ar3, b3, 1, bufB, (float*)d_out,
              el, er, menc, sb, ex, src, dst, N, E, false, stream);
}

// Round 4
// 1047.004 us; speedup vs baseline: 2.0898x; 2.0898x over previous
//
#include <hip/hip_runtime.h>
#include <hip/hip_bf16.h>

#define LEAKY 0.2f

// ---------------- CSR build ----------------

__global__ void k_zero_int(int* __restrict__ p, int n) {
    int i = blockIdx.x * blockDim.x + threadIdx.x;
    if (i < n) p[i] = 0;
}

__global__ void k_hist(const int* __restrict__ dst, int* __restrict__ cnt, int E, int N) {
    int e = blockIdx.x * blockDim.x + threadIdx.x;
    if (e >= E) return;
    int dn = dst[e];
    if ((unsigned)dn < (unsigned)N) atomicAdd(&cnt[dn], 1);
}

// single-block exclusive scan over cnt[0..N) -> row_start[0..N], cursor copy
__global__ __launch_bounds__(1024)
void k_scan(const int* __restrict__ cnt, int* __restrict__ row_start,
            int* __restrict__ cursor, int N) {
    __shared__ int smem[1024];
    __shared__ int carry;
    const int tid = threadIdx.x;
    if (tid == 0) carry = 0;
    __syncthreads();
    for (int base = 0; base < N; base += 1024) {
        int c = carry;
        int i = base + tid;
        int v = (i < N) ? cnt[i] : 0;
        smem[tid] = v;
        __syncthreads();
        #pragma unroll
        for (int off = 1; off < 1024; off <<= 1) {
            int t = (tid >= off) ? smem[tid - off] : 0;
            __syncthreads();
            smem[tid] += t;
            __syncthreads();
        }
        int incl = smem[tid];
        if (i < N) {
            int excl = c + incl - v;
            row_start[i] = excl;
            cursor[i] = excl;
        }
        int tot = smem[1023];
        __syncthreads();
        if (tid == 0) carry = c + tot;
        __syncthreads();
    }
    if (tid == 0) row_start[N] = carry;
}

__global__ void k_scatter(const int* __restrict__ src, const int* __restrict__ dst,
                          int* __restrict__ cursor, int* __restrict__ src_sorted,
                          int* __restrict__ dst_sorted, int E, int N) {
    int e = blockIdx.x * blockDim.x + threadIdx.x;
    if (e >= E) return;
    int dn = dst[e];
    if ((unsigned)dn >= (unsigned)N) return;
    int pos = atomicAdd(&cursor[dn], 1);
    src_sorted[pos] = src[e];
    dst_sorted[pos] = dn;
}

// ---------------- GEMM: C[N,M] = A[N,K] * B[K,M], all f32 ----------------
// 64x64 tile per 256-thread block, K-tile 16, 4x4 micro-tile per thread.

__global__ __launch_bounds__(256)
void k_gemm(const float* __restrict__ A, const float* __restrict__ B,
            float* __restrict__ C, int N, int K, int M) {
    __shared__ float As[64][17];
    __shared__ float Bs[16][65];
    const int tid = threadIdx.x;
    const int tx = tid & 15, ty = tid >> 4;
    const int row0 = blockIdx.y * 64;
    const int col0 = blockIdx.x * 64;

    const int ar = (tid * 4) >> 4;
    const int ac = (tid * 4) & 15;
    const int br = (tid * 4) >> 6;
    const int bc = (tid * 4) & 63;

    float acc[4][4] = {};

    for (int k0 = 0; k0 < K; k0 += 16) {
        float4 av = make_float4(0.f, 0.f, 0.f, 0.f);
        int gr = row0 + ar;
        if (gr < N) av = *(const float4*)(A + (size_t)gr * K + k0 + ac);
        As[ar][ac]     = av.x;
        As[ar][ac + 1] = av.y;
        As[ar][ac + 2] = av.z;
        As[ar][ac + 3] = av.w;

        float4 bv = *(const float4*)(B + (size_t)(k0 + br) * M + col0 + bc);
        Bs[br][bc]     = bv.x;
        Bs[br][bc + 1] = bv.y;
        Bs[br][bc + 2] = bv.z;
        Bs[br][bc + 3] = bv.w;
        __syncthreads();

        #pragma unroll
        for (int kk = 0; kk < 16; ++kk) {
            float a[4], b[4];
            #pragma unroll
            for (int i = 0; i < 4; ++i) a[i] = As[ty * 4 + i][kk];
            #pragma unroll
            for (int j = 0; j < 4; ++j) b[j] = Bs[kk][tx * 4 + j];
            #pragma unroll
            for (int i = 0; i < 4; ++i)
                #pragma unroll
                for (int j = 0; j < 4; ++j)
                    acc[i][j] += a[i] * b[j];
        }
        __syncthreads();
    }

    #pragma unroll
    for (int i = 0; i < 4; ++i) {
        int r = row0 + ty * 4 + i;
        if (r < N) {
            #pragma unroll
            for (int j = 0; j < 4; ++j)
                C[(size_t)r * M + col0 + tx * 4 + j] = acc[i][j];
        }
    }
}

// ---------------- attention pieces (CSR, atomic-free) ----------------

__global__ void k_el_er(const float* __restrict__ feat, const float* __restrict__ al,
                        const float* __restrict__ ar, float* __restrict__ el,
                        float* __restrict__ er, int N, int H) {
    int idx = blockIdx.x * blockDim.x + threadIdx.x;
    if (idx >= N * H) return;
    int h = idx % H;
    int n = idx / H;
    const float* f = feat + (size_t)n * (H * 64) + h * 64;
    float sl = 0.f, sr = 0.f;
    #pragma unroll 8
    for (int d = 0; d < 64; ++d) {
        float v = f[d];
        sl += v * al[h * 64 + d];
        sr += v * ar[h * 64 + d];
    }
    el[idx] = sl;
    er[idx] = sr;
}

// per (node, head): max then sum over incoming edges (CSR traversal)
__global__ void k_node_ms(const int* __restrict__ row_start, const int* __restrict__ src_sorted,
                          const float* __restrict__ el, const float* __restrict__ er,
                          float* __restrict__ m, float* __restrict__ s, int N, int H) {
    int idx = blockIdx.x * blockDim.x + threadIdx.x;
    if (idx >= N * H) return;
    int n = idx / H;
    int h = idx - n * H;
    float erv = er[idx];
    int b0 = row_start[n], b1 = row_start[n + 1];
    float mx = -INFINITY;
    for (int i = b0; i < b1; ++i) {
        float x = el[src_sorted[i] * H + h] + erv;
        x = (x > 0.f) ? x : LEAKY * x;
        mx = fmaxf(mx, x);
    }
    float sum = 0.f;
    for (int i = b0; i < b1; ++i) {
        float x = el[src_sorted[i] * H + h] + erv;
        x = (x > 0.f) ? x : LEAKY * x;
        sum += expf(fminf(x - mx, 0.f));
    }
    m[idx] = mx;
    s[idx] = sum;
}

// per (sorted-edge, head): normalized weight, stored in sorted order
__global__ void k_edge_w(const int* __restrict__ src_sorted, const int* __restrict__ dst_sorted,
                         const float* __restrict__ el, const float* __restrict__ er,
                         const float* __restrict__ m, const float* __restrict__ s,
                         float* __restrict__ w, int EH, int H) {
    int idx = blockIdx.x * blockDim.x + threadIdx.x;
    if (idx >= EH) return;
    int e = idx / H;
    int h = idx - e * H;
    int sn = src_sorted[e], dn = dst_sorted[e];
    float x = el[sn * H + h] + er[dn * H + h];
    x = (x > 0.f) ? x : LEAKY * x;
    float rs = 1.0f / fmaxf(s[dn * H + h], 1e-30f);
    w[idx] = expf(fminf(x - m[dn * H + h], 0.f)) * rs;
}

// one block of M=H*64 threads per dst node; thread owns one (h,d) output slot
__global__ void k_agg_csr(const int* __restrict__ row_start, const int* __restrict__ src_sorted,
                          const float* __restrict__ feat, const float* __restrict__ w,
                          const float* __restrict__ bias, float* __restrict__ out,
                          int H, int do_relu) {
    const int n = blockIdx.x;
    const int tid = threadIdx.x;
    const int M = H * 64;
    const int h = tid >> 6;
    float acc = bias[tid];
    int b0 = row_start[n], b1 = row_start[n + 1];
    for (int i = b0; i < b1; ++i) {
        int sn = src_sorted[i];
        float wv = w[(size_t)i * H + h];
        acc += feat[(size_t)sn * M + tid] * wv;
    }
    if (do_relu) acc = fmaxf(acc, 0.f);
    out[(size_t)n * M + tid] = acc;
}

// ---------------- host side ----------------

static void run_layer(const float* A, int K, const float* W,
                      const float* al_, const float* ar_, const float* b_, int H,
                      float* feat, float* rstOut,
                      float* el, float* er, float* m, float* s, float* w,
                      const int* row_start, const int* src_sorted, const int* dst_sorted,
                      int N, int E, bool do_relu, hipStream_t stream) {
    const int M = H * 64;
    dim3 gg(M / 64, (N + 63) / 64);
    k_gemm<<<gg, 256, 0, stream>>>(A, W, feat, N, K, M);

    int nh = N * H;
    k_el_er<<<(nh + 255) / 256, 256, 0, stream>>>(feat, al_, ar_, el, er, N, H);
    k_node_ms<<<(nh + 255) / 256, 256, 0, stream>>>(row_start, src_sorted, el, er, m, s, N, H);

    int eh = E * H;
    k_edge_w<<<(eh + 255) / 256, 256, 0, stream>>>(src_sorted, dst_sorted, el, er, m, s, w, eh, H);

    k_agg_csr<<<N, M, 0, stream>>>(row_start, src_sorted, feat, w, b_, rstOut, H, do_relu ? 1 : 0);
}

extern "C" void kernel_launch(void* const* d_in, const int* in_sizes, int n_in,
                              void* d_out, int out_size, void* d_ws, size_t ws_size,
                              hipStream_t stream) {
    const float* features = (const float*)d_in[0];
    const int*   src = (const int*)d_in[1];
    const int*   dst = (const int*)d_in[2];
    const float* W1  = (const float*)d_in[3];
    const float* al1 = (const float*)d_in[4];
    const float* ar1 = (const float*)d_in[5];
    const float* b1  = (const float*)d_in[6];
    const float* W2  = (const float*)d_in[7];
    const float* al2 = (const float*)d_in[8];
    const float* ar2 = (const float*)d_in[9];
    const float* b2  = (const float*)d_in[10];
    const float* W3  = (const float*)d_in[11];
    const float* al3 = (const float*)d_in[12];
    const float* ar3 = (const float*)d_in[13];
    const float* b3  = (const float*)d_in[14];

    const int N = in_sizes[0] / 128;   // 50000
    const int E = in_sizes[1];         // 800000

    float* ws   = (float*)d_ws;
    size_t n256 = (size_t)N * 256;
    float* bufA = ws;                        // [N,256]
    float* bufB = bufA + n256;               // [N,256]
    float* el   = bufB + n256;               // [N,4]
    float* er   = el + (size_t)N * 4;        // [N,4]
    float* m    = er + (size_t)N * 4;        // [N,4]
    float* s    = m  + (size_t)N * 4;        // [N,4]
    float* w    = s  + (size_t)N * 4;        // [E,4]
    int* cnt        = (int*)(w + (size_t)E * 4);   // [N]
    int* row_start  = cnt + N;                      // [N+1]
    int* cursor     = row_start + N + 1;            // [N]
    int* src_sorted = cursor + N;                   // [E]
    int* dst_sorted = src_sorted + E;               // [E]

    // ---- build dst-CSR (every call; deterministic, graph-capture safe) ----
    k_zero_int<<<(N + 255) / 256, 256, 0, stream>>>(cnt, N);
    k_hist<<<(E + 255) / 256, 256, 0, stream>>>(dst, cnt, E, N);
    k_scan<<<1, 1024, 0, stream>>>(cnt, row_start, cursor, N);
    k_scatter<<<(E + 255) / 256, 256, 0, stream>>>(src, dst, cursor, src_sorted, dst_sorted, E, N);

    // layer 1: A=features[N,128] -> feat=bufB[N,256] -> rst=bufA[N,256] (+relu)
    run_layer(features, 128, W1, al1, ar1, b1, 4, bufB, bufA,
              el, er, m, s, w, row_start, src_sorted, dst_sorted, N, E, true, stream);
    // layer 2
    run_layer(bufA, 256, W2, al2, ar2, b2, 4, bufB, bufA,
              el, er, m, s, w, row_start, src_sorted, dst_sorted, N, E, true, stream);
    // layer 3: H=1; mean over 1 head is identity -> write straight to d_out
    run_layer(bufA, 256, W3, al3, ar3, b3, 1, bufB, (float*)d_out,
              el, er, m, s, w, row_start, src_sorted, dst_sorted, N, E, false, stream);
}

// Round 5
// 930.627 us; speedup vs baseline: 2.3511x; 1.1251x over previous
//
#include <hip/hip_runtime.h>
#include <hip/hip_bf16.h>

#define LEAKY 0.2f

// ---------------- CSR build ----------------

__global__ void k_zero_int(int* __restrict__ p, int n) {
    int i = blockIdx.x * blockDim.x + threadIdx.x;
    if (i < n) p[i] = 0;
}

__global__ void k_hist(const int* __restrict__ dst, int* __restrict__ cnt, int E, int N) {
    int e = blockIdx.x * blockDim.x + threadIdx.x;
    if (e >= E) return;
    int dn = dst[e];
    if ((unsigned)dn < (unsigned)N) atomicAdd(&cnt[dn], 1);
}

// single-block exclusive scan, shuffle-based (wave scan + cross-wave combine)
__global__ __launch_bounds__(1024)
void k_scan(const int* __restrict__ cnt, int* __restrict__ row_start,
            int* __restrict__ cursor, int N) {
    __shared__ int wsum[16];
    __shared__ int carry_s;
    const int tid  = threadIdx.x;
    const int wave = tid >> 6;
    const int lane = tid & 63;
    if (tid == 0) carry_s = 0;
    __syncthreads();
    for (int base = 0; base < N; base += 1024) {
        int i = base + tid;
        int v = (i < N) ? cnt[i] : 0;
        // inclusive wave scan
        int x = v;
        #pragma unroll
        for (int off = 1; off < 64; off <<= 1) {
            int t = __shfl_up(x, off, 64);
            if (lane >= off) x += t;
        }
        if (lane == 63) wsum[wave] = x;
        __syncthreads();
        if (wave == 0 && lane < 16) {
            int y = wsum[lane];
            #pragma unroll
            for (int off = 1; off < 16; off <<= 1) {
                int t = __shfl_up(y, off, 64);
                if (lane >= off) y += t;
            }
            wsum[lane] = y;  // inclusive over wave totals
        }
        __syncthreads();
        int carry = carry_s;
        int wbase = (wave > 0) ? wsum[wave - 1] : 0;
        int excl  = carry + wbase + x - v;
        if (i < N) { row_start[i] = excl; cursor[i] = excl; }
        int tot = wsum[15];
        __syncthreads();
        if (tid == 0) carry_s = carry + tot;
        __syncthreads();
    }
    if (tid == 0) row_start[N] = carry_s;
}

__global__ void k_scatter(const int* __restrict__ src, const int* __restrict__ dst,
                          int* __restrict__ cursor, int* __restrict__ src_sorted,
                          int* __restrict__ dst_sorted, int E, int N) {
    int e = blockIdx.x * blockDim.x + threadIdx.x;
    if (e >= E) return;
    int dn = dst[e];
    if ((unsigned)dn >= (unsigned)N) return;
    int pos = atomicAdd(&cursor[dn], 1);
    src_sorted[pos] = src[e];
    dst_sorted[pos] = dn;
}

// ---------------- GEMM: C[N,M] = A[N,K] * B[K,M], all f32 ----------------
// BM=128 x BN=64 tile, BK=16, 256 threads, 8x4 micro-tile per thread.
// A staged k-major in LDS so fragment reads are contiguous b128s.

__global__ __launch_bounds__(256)
void k_gemm(const float* __restrict__ A, const float* __restrict__ B,
            float* __restrict__ C, int N, int K, int M) {
    __shared__ float As[16][132];   // [k][row]
    __shared__ float Bs[16][68];    // [k][col]
    const int tid = threadIdx.x;
    const int tx = tid & 15;        // col-group (4 cols)
    const int ty = tid >> 4;        // row-group (8 rows)
    const int row0 = blockIdx.y * 128;
    const int col0 = blockIdx.x * 64;

    const int arow = tid >> 2;          // 0..63 (two passes)
    const int acol = (tid & 3) * 4;     // 0,4,8,12
    const int brow = tid >> 4;          // 0..15
    const int bcol = (tid & 15) * 4;

    float acc[8][4] = {};

    for (int k0 = 0; k0 < K; k0 += 16) {
        #pragma unroll
        for (int p = 0; p < 2; ++p) {
            int r = arow + p * 64;
            int gr = row0 + r;
            float4 av = make_float4(0.f, 0.f, 0.f, 0.f);
            if (gr < N) av = *(const float4*)(A + (size_t)gr * K + k0 + acol);
            As[acol + 0][r] = av.x;
            As[acol + 1][r] = av.y;
            As[acol + 2][r] = av.z;
            As[acol + 3][r] = av.w;
        }
        {
            float4 bv = *(const float4*)(B + (size_t)(k0 + brow) * M + col0 + bcol);
            Bs[brow][bcol + 0] = bv.x;
            Bs[brow][bcol + 1] = bv.y;
            Bs[brow][bcol + 2] = bv.z;
            Bs[brow][bcol + 3] = bv.w;
        }
        __syncthreads();

        #pragma unroll
        for (int kk = 0; kk < 16; ++kk) {
            float a[8], b[4];
            #pragma unroll
            for (int i = 0; i < 8; ++i) a[i] = As[kk][ty * 8 + i];
            #pragma unroll
            for (int j = 0; j < 4; ++j) b[j] = Bs[kk][tx * 4 + j];
            #pragma unroll
            for (int i = 0; i < 8; ++i)
                #pragma unroll
                for (int j = 0; j < 4; ++j)
                    acc[i][j] = fmaf(a[i], b[j], acc[i][j]);
        }
        __syncthreads();
    }

    #pragma unroll
    for (int i = 0; i < 8; ++i) {
        int r = row0 + ty * 8 + i;
        if (r < N) {
            float4 o = make_float4(acc[i][0], acc[i][1], acc[i][2], acc[i][3]);
            *(float4*)(C + (size_t)r * M + col0 + tx * 4) = o;
        }
    }
}

// ---------------- attention pieces (CSR, atomic-free) ----------------

// one wave per (node,head): lane = d, coalesced feat read, shuffle reduce
__global__ __launch_bounds__(256)
void k_el_er(const float* __restrict__ feat, const float* __restrict__ al,
             const float* __restrict__ ar, float* __restrict__ el,
             float* __restrict__ er, int NH, int H) {
    int g = blockIdx.x * 4 + (threadIdx.x >> 6);   // g = n*H + h
    int lane = threadIdx.x & 63;
    if (g >= NH) return;
    int h = g % H;
    float v  = feat[(size_t)g * 64 + lane];
    float sl = v * al[h * 64 + lane];
    float sr = v * ar[h * 64 + lane];
    #pragma unroll
    for (int off = 32; off; off >>= 1) {
        sl += __shfl_down(sl, off, 64);
        sr += __shfl_down(sr, off, 64);
    }
    if (lane == 0) { el[g] = sl; er[g] = sr; }
}

// per (node, head): online softmax max+sum over incoming edges (single pass)
__global__ void k_node_ms(const int* __restrict__ row_start, const int* __restrict__ src_sorted,
                          const float* __restrict__ el, const float* __restrict__ er,
                          float* __restrict__ m, float* __restrict__ s, int N, int H) {
    int idx = blockIdx.x * blockDim.x + threadIdx.x;
    if (idx >= N * H) return;
    int n = idx / H;
    int h = idx - n * H;
    float erv = er[idx];
    int b0 = row_start[n], b1 = row_start[n + 1];
    float mx = -INFINITY, sum = 0.f;
    for (int i = b0; i < b1; ++i) {
        float x = el[src_sorted[i] * H + h] + erv;
        x = (x > 0.f) ? x : LEAKY * x;
        if (x > mx) { sum = sum * __expf(mx - x) + 1.f; mx = x; }
        else        { sum += __expf(x - mx); }
    }
    m[idx] = mx;
    s[idx] = sum;
}

// per (sorted-edge, head): normalized weight, stored in sorted order
__global__ void k_edge_w(const int* __restrict__ src_sorted, const int* __restrict__ dst_sorted,
                         const float* __restrict__ el, const float* __restrict__ er,
                         const float* __restrict__ m, const float* __restrict__ s,
                         float* __restrict__ w, int EH, int H) {
    int idx = blockIdx.x * blockDim.x + threadIdx.x;
    if (idx >= EH) return;
    int e = idx / H;
    int h = idx - e * H;
    int sn = src_sorted[e], dn = dst_sorted[e];
    float x = el[sn * H + h] + er[dn * H + h];
    x = (x > 0.f) ? x : LEAKY * x;
    float rs = 1.0f / fmaxf(s[dn * H + h], 1e-30f);
    w[idx] = expf(fminf(x - m[dn * H + h], 0.f)) * rs;
}

// one block of M=H*64 threads per dst node; thread owns one (h,d) output slot
__global__ void k_agg_csr(const int* __restrict__ row_start, const int* __restrict__ src_sorted,
                          const float* __restrict__ feat, const float* __restrict__ w,
                          const float* __restrict__ bias, float* __restrict__ out,
                          int H, int do_relu) {
    const int n = blockIdx.x;
    const int tid = threadIdx.x;
    const int M = H * 64;
    const int h = tid >> 6;
    float acc = bias[tid];
    int b0 = row_start[n], b1 = row_start[n + 1];
    for (int i = b0; i < b1; ++i) {
        int sn = src_sorted[i];
        float wv = w[(size_t)i * H + h];
        acc += feat[(size_t)sn * M + tid] * wv;
    }
    if (do_relu) acc = fmaxf(acc, 0.f);
    out[(size_t)n * M + tid] = acc;
}

// ---------------- host side ----------------

static void run_layer(const float* A, int K, const float* W,
                      const float* al_, const float* ar_, const float* b_, int H,
                      float* feat, float* rstOut,
                      float* el, float* er, float* m, float* s, float* w,
                      const int* row_start, const int* src_sorted, const int* dst_sorted,
                      int N, int E, bool do_relu, hipStream_t stream) {
    const int M = H * 64;
    dim3 gg(M / 64, (N + 127) / 128);
    k_gemm<<<gg, 256, 0, stream>>>(A, W, feat, N, K, M);

    int nh = N * H;
    k_el_er<<<(nh + 3) / 4, 256, 0, stream>>>(feat, al_, ar_, el, er, nh, H);
    k_node_ms<<<(nh + 255) / 256, 256, 0, stream>>>(row_start, src_sorted, el, er, m, s, N, H);

    int eh = E * H;
    k_edge_w<<<(eh + 255) / 256, 256, 0, stream>>>(src_sorted, dst_sorted, el, er, m, s, w, eh, H);

    k_agg_csr<<<N, M, 0, stream>>>(row_start, src_sorted, feat, w, b_, rstOut, H, do_relu ? 1 : 0);
}

extern "C" void kernel_launch(void* const* d_in, const int* in_sizes, int n_in,
                              void* d_out, int out_size, void* d_ws, size_t ws_size,
                              hipStream_t stream) {
    const float* features = (const float*)d_in[0];
    const int*   src = (const int*)d_in[1];
    const int*   dst = (const int*)d_in[2];
    const float* W1  = (const float*)d_in[3];
    const float* al1 = (const float*)d_in[4];
    const float* ar1 = (const float*)d_in[5];
    const float* b1  = (const float*)d_in[6];
    const float* W2  = (const float*)d_in[7];
    const float* al2 = (const float*)d_in[8];
    const float* ar2 = (const float*)d_in[9];
    const float* b2  = (const float*)d_in[10];
    const float* W3  = (const float*)d_in[11];
    const float* al3 = (const float*)d_in[12];
    const float* ar3 = (const float*)d_in[13];
    const float* b3  = (const float*)d_in[14];

    const int N = in_sizes[0] / 128;   // 50000
    const int E = in_sizes[1];         // 800000

    float* ws   = (float*)d_ws;
    size_t n256 = (size_t)N * 256;
    float* bufA = ws;                        // [N,256]
    float* bufB = bufA + n256;               // [N,256]
    float* el   = bufB + n256;               // [N,4]
    float* er   = el + (size_t)N * 4;        // [N,4]
    float* m    = er + (size_t)N * 4;        // [N,4]
    float* s    = m  + (size_t)N * 4;        // [N,4]
    float* w    = s  + (size_t)N * 4;        // [E,4]
    int* cnt        = (int*)(w + (size_t)E * 4);   // [N]
    int* row_start  = cnt + N;                      // [N+1]
    int* cursor     = row_start + N + 1;            // [N]
    int* src_sorted = cursor + N;                   // [E]
    int* dst_sorted = src_sorted + E;               // [E]

    // ---- build dst-CSR (every call; deterministic, graph-capture safe) ----
    k_zero_int<<<(N + 255) / 256, 256, 0, stream>>>(cnt, N);
    k_hist<<<(E + 255) / 256, 256, 0, stream>>>(dst, cnt, E, N);
    k_scan<<<1, 1024, 0, stream>>>(cnt, row_start, cursor, N);
    k_scatter<<<(E + 255) / 256, 256, 0, stream>>>(src, dst, cursor, src_sorted, dst_sorted, E, N);

    // layer 1: A=features[N,128] -> feat=bufB[N,256] -> rst=bufA[N,256] (+relu)
    run_layer(features, 128, W1, al1, ar1, b1, 4, bufB, bufA,
              el, er, m, s, w, row_start, src_sorted, dst_sorted, N, E, true, stream);
    // layer 2
    run_layer(bufA, 256, W2, al2, ar2, b2, 4, bufB, bufA,
              el, er, m, s, w, row_start, src_sorted, dst_sorted, N, E, true, stream);
    // layer 3: H=1; mean over 1 head is identity -> write straight to d_out
    run_layer(bufA, 256, W3, al3, ar3, b3, 1, bufB, (float*)d_out,
              el, er, m, s, w, row_start, src_sorted, dst_sorted, N, E, false, stream);
}

// Round 6
// 868.404 us; speedup vs baseline: 2.5196x; 1.0717x over previous
//
#include <hip/hip_runtime.h>
#include <hip/hip_bf16.h>

#define LEAKY 0.2f

// ---------------- CSR build ----------------

__global__ void k_zero_int(int* __restrict__ p, int n) {
    int i = blockIdx.x * blockDim.x + threadIdx.x;
    if (i < n) p[i] = 0;
}

__global__ void k_hist(const int* __restrict__ dst, int* __restrict__ cnt, int E, int N) {
    int e = blockIdx.x * blockDim.x + threadIdx.x;
    if (e >= E) return;
    int dn = dst[e];
    if ((unsigned)dn < (unsigned)N) atomicAdd(&cnt[dn], 1);
}

// single-block exclusive scan, shuffle-based (wave scan + cross-wave combine)
__global__ __launch_bounds__(1024)
void k_scan(const int* __restrict__ cnt, int* __restrict__ row_start,
            int* __restrict__ cursor, int N) {
    __shared__ int wsum[16];
    __shared__ int carry_s;
    const int tid  = threadIdx.x;
    const int wave = tid >> 6;
    const int lane = tid & 63;
    if (tid == 0) carry_s = 0;
    __syncthreads();
    for (int base = 0; base < N; base += 1024) {
        int i = base + tid;
        int v = (i < N) ? cnt[i] : 0;
        int x = v;
        #pragma unroll
        for (int off = 1; off < 64; off <<= 1) {
            int t = __shfl_up(x, off, 64);
            if (lane >= off) x += t;
        }
        if (lane == 63) wsum[wave] = x;
        __syncthreads();
        if (wave == 0 && lane < 16) {
            int y = wsum[lane];
            #pragma unroll
            for (int off = 1; off < 16; off <<= 1) {
                int t = __shfl_up(y, off, 64);
                if (lane >= off) y += t;
            }
            wsum[lane] = y;
        }
        __syncthreads();
        int carry = carry_s;
        int wbase = (wave > 0) ? wsum[wave - 1] : 0;
        int excl  = carry + wbase + x - v;
        if (i < N) { row_start[i] = excl; cursor[i] = excl; }
        int tot = wsum[15];
        __syncthreads();
        if (tid == 0) carry_s = carry + tot;
        __syncthreads();
    }
    if (tid == 0) row_start[N] = carry_s;
}

__global__ void k_scatter(const int* __restrict__ src, const int* __restrict__ dst,
                          int* __restrict__ cursor, int* __restrict__ src_sorted,
                          int E, int N) {
    int e = blockIdx.x * blockDim.x + threadIdx.x;
    if (e >= E) return;
    int dn = dst[e];
    if ((unsigned)dn >= (unsigned)N) return;
    int pos = atomicAdd(&cursor[dn], 1);
    src_sorted[pos] = src[e];
}

// ---------------- GEMM kernels (f32) ----------------
// 128x64 tile, 8x4 micro-tile (used for M=64)

__global__ __launch_bounds__(256)
void k_gemm64(const float* __restrict__ A, const float* __restrict__ B,
              float* __restrict__ C, int N, int K, int M) {
    __shared__ float As[16][132];
    __shared__ float Bs[16][68];
    const int tid = threadIdx.x;
    const int tx = tid & 15;
    const int ty = tid >> 4;
    const int row0 = blockIdx.y * 128;
    const int col0 = blockIdx.x * 64;

    const int arow = tid >> 2;
    const int acol = (tid & 3) * 4;
    const int brow = tid >> 4;
    const int bcol = (tid & 15) * 4;

    float acc[8][4] = {};

    for (int k0 = 0; k0 < K; k0 += 16) {
        #pragma unroll
        for (int p = 0; p < 2; ++p) {
            int r = arow + p * 64;
            int gr = row0 + r;
            float4 av = make_float4(0.f, 0.f, 0.f, 0.f);
            if (gr < N) av = *(const float4*)(A + (size_t)gr * K + k0 + acol);
            As[acol + 0][r] = av.x;
            As[acol + 1][r] = av.y;
            As[acol + 2][r] = av.z;
            As[acol + 3][r] = av.w;
        }
        {
            float4 bv = *(const float4*)(B + (size_t)(k0 + brow) * M + col0 + bcol);
            Bs[brow][bcol + 0] = bv.x;
            Bs[brow][bcol + 1] = bv.y;
            Bs[brow][bcol + 2] = bv.z;
            Bs[brow][bcol + 3] = bv.w;
        }
        __syncthreads();

        #pragma unroll
        for (int kk = 0; kk < 16; ++kk) {
            float a[8], b[4];
            #pragma unroll
            for (int i = 0; i < 8; ++i) a[i] = As[kk][ty * 8 + i];
            #pragma unroll
            for (int j = 0; j < 4; ++j) b[j] = Bs[kk][tx * 4 + j];
            #pragma unroll
            for (int i = 0; i < 8; ++i)
                #pragma unroll
                for (int j = 0; j < 4; ++j)
                    acc[i][j] = fmaf(a[i], b[j], acc[i][j]);
        }
        __syncthreads();
    }

    #pragma unroll
    for (int i = 0; i < 8; ++i) {
        int r = row0 + ty * 8 + i;
        if (r < N) {
            float4 o = make_float4(acc[i][0], acc[i][1], acc[i][2], acc[i][3]);
            *(float4*)(C + (size_t)r * M + col0 + tx * 4) = o;
        }
    }
}

// 128x128 tile, 8x8 micro-tile (used for M multiple of 128)
__global__ __launch_bounds__(256)
void k_gemm128(const float* __restrict__ A, const float* __restrict__ B,
               float* __restrict__ C, int N, int K, int M) {
    __shared__ float As[16][132];
    __shared__ float Bs[16][132];
    const int tid = threadIdx.x;
    const int tx = tid & 15;      // 16 col-groups of 8
    const int ty = tid >> 4;      // 16 row-groups of 8
    const int row0 = blockIdx.y * 128;
    const int col0 = blockIdx.x * 128;

    const int arow = tid >> 2;          // 0..63, +64 second pass
    const int acol = (tid & 3) * 4;
    const int brow = tid >> 5;          // 0..7, +8 second pass
    const int bcol = (tid & 31) * 4;

    float acc[8][8] = {};

    for (int k0 = 0; k0 < K; k0 += 16) {
        #pragma unroll
        for (int p = 0; p < 2; ++p) {
            int r = arow + p * 64;
            int gr = row0 + r;
            float4 av = make_float4(0.f, 0.f, 0.f, 0.f);
            if (gr < N) av = *(const float4*)(A + (size_t)gr * K + k0 + acol);
            As[acol + 0][r] = av.x;
            As[acol + 1][r] = av.y;
            As[acol + 2][r] = av.z;
            As[acol + 3][r] = av.w;
        }
        #pragma unroll
        for (int p = 0; p < 2; ++p) {
            int r = brow + p * 8;
            float4 bv = *(const float4*)(B + (size_t)(k0 + r) * M + col0 + bcol);
            Bs[r][bcol + 0] = bv.x;
            Bs[r][bcol + 1] = bv.y;
            Bs[r][bcol + 2] = bv.z;
            Bs[r][bcol + 3] = bv.w;
        }
        __syncthreads();

        #pragma unroll
        for (int kk = 0; kk < 16; ++kk) {
            float a[8], b[8];
            #pragma unroll
            for (int i = 0; i < 8; ++i) a[i] = As[kk][ty * 8 + i];
            #pragma unroll
            for (int j = 0; j < 8; ++j) b[j] = Bs[kk][tx * 8 + j];
            #pragma unroll
            for (int i = 0; i < 8; ++i)
                #pragma unroll
                for (int j = 0; j < 8; ++j)
                    acc[i][j] = fmaf(a[i], b[j], acc[i][j]);
        }
        __syncthreads();
    }

    #pragma unroll
    for (int i = 0; i < 8; ++i) {
        int r = row0 + ty * 8 + i;
        if (r < N) {
            *(float4*)(C + (size_t)r * M + col0 + tx * 8) =
                make_float4(acc[i][0], acc[i][1], acc[i][2], acc[i][3]);
            *(float4*)(C + (size_t)r * M + col0 + tx * 8 + 4) =
                make_float4(acc[i][4], acc[i][5], acc[i][6], acc[i][7]);
        }
    }
}

// ---------------- attention pieces (CSR, atomic-free) ----------------

// one wave per (node,head): lane = d, coalesced feat read, shuffle reduce
__global__ __launch_bounds__(256)
void k_el_er(const float* __restrict__ feat, const float* __restrict__ al,
             const float* __restrict__ ar, float* __restrict__ el,
             float* __restrict__ er, int NH, int H) {
    int g = blockIdx.x * 4 + (threadIdx.x >> 6);
    int lane = threadIdx.x & 63;
    if (g >= NH) return;
    int h = g % H;
    float v  = feat[(size_t)g * 64 + lane];
    float sl = v * al[h * 64 + lane];
    float sr = v * ar[h * 64 + lane];
    #pragma unroll
    for (int off = 32; off; off >>= 1) {
        sl += __shfl_down(sl, off, 64);
        sr += __shfl_down(sr, off, 64);
    }
    if (lane == 0) { el[g] = sl; er[g] = sr; }
}

// per (node, head): online softmax max+sum over incoming edges
__global__ void k_node_ms(const int* __restrict__ row_start, const int* __restrict__ src_sorted,
                          const float* __restrict__ el, const float* __restrict__ er,
                          float* __restrict__ m, float* __restrict__ s, int N, int H) {
    int idx = blockIdx.x * blockDim.x + threadIdx.x;
    if (idx >= N * H) return;
    int n = idx / H;
    int h = idx - n * H;
    float erv = er[idx];
    int b0 = row_start[n], b1 = row_start[n + 1];
    float mx = -INFINITY, sum = 0.f;
    for (int i = b0; i < b1; ++i) {
        float x = el[src_sorted[i] * H + h] + erv;
        x = (x > 0.f) ? x : LEAKY * x;
        if (x > mx) { sum = sum * __expf(mx - x) + 1.f; mx = x; }
        else        { sum += __expf(x - mx); }
    }
    m[idx] = mx;
    s[idx] = sum;
}

// Aggregation with fused edge-weight computation.
// 256 threads = (256/M) node-groups; each group of M threads owns one dst node,
// thread owns one (h,d) slot. 4-wide software pipeline on the edge loop.
__global__ __launch_bounds__(256)
void k_agg_csr(const int* __restrict__ row_start, const int* __restrict__ src_sorted,
               const float* __restrict__ feat, const float* __restrict__ el,
               const float* __restrict__ er, const float* __restrict__ m,
               const float* __restrict__ s, const float* __restrict__ bias,
               float* __restrict__ out, int H, int N, int do_relu) {
    const int M = H * 64;
    const int G = 256 / M;
    const int grp = threadIdx.x / M;
    const int tid = threadIdx.x - grp * M;
    const int n = blockIdx.x * G + grp;
    if (n >= N) return;
    const int h = tid >> 6;

    const float mv  = m[n * H + h];
    const float rs  = 1.0f / fmaxf(s[n * H + h], 1e-30f);
    const float erv = er[n * H + h];

    float acc = bias[tid];
    int b0 = row_start[n], b1 = row_start[n + 1];
    int i = b0;
    for (; i + 4 <= b1; i += 4) {
        int s0 = src_sorted[i], s1 = src_sorted[i + 1];
        int s2 = src_sorted[i + 2], s3 = src_sorted[i + 3];
        float f0 = feat[(size_t)s0 * M + tid];
        float f1 = feat[(size_t)s1 * M + tid];
        float f2 = feat[(size_t)s2 * M + tid];
        float f3 = feat[(size_t)s3 * M + tid];
        float x0 = el[s0 * H + h] + erv; x0 = (x0 > 0.f) ? x0 : LEAKY * x0;
        float x1 = el[s1 * H + h] + erv; x1 = (x1 > 0.f) ? x1 : LEAKY * x1;
        float x2 = el[s2 * H + h] + erv; x2 = (x2 > 0.f) ? x2 : LEAKY * x2;
        float x3 = el[s3 * H + h] + erv; x3 = (x3 > 0.f) ? x3 : LEAKY * x3;
        float w0 = __expf(x0 - mv) * rs;
        float w1 = __expf(x1 - mv) * rs;
        float w2 = __expf(x2 - mv) * rs;
        float w3 = __expf(x3 - mv) * rs;
        acc = fmaf(f0, w0, acc);
        acc = fmaf(f1, w1, acc);
        acc = fmaf(f2, w2, acc);
        acc = fmaf(f3, w3, acc);
    }
    for (; i < b1; ++i) {
        int sn = src_sorted[i];
        float f = feat[(size_t)sn * M + tid];
        float x = el[sn * H + h] + erv; x = (x > 0.f) ? x : LEAKY * x;
        acc = fmaf(f, __expf(x - mv) * rs, acc);
    }
    if (do_relu) acc = fmaxf(acc, 0.f);
    out[(size_t)n * M + tid] = acc;
}

// ---------------- host side ----------------

static void run_layer(const float* A, int K, const float* W,
                      const float* al_, const float* ar_, const float* b_, int H,
                      float* feat, float* rstOut,
                      float* el, float* er, float* m, float* s,
                      const int* row_start, const int* src_sorted,
                      int N, int E, bool do_relu, hipStream_t stream) {
    const int M = H * 64;
    if (M % 128 == 0) {
        dim3 gg(M / 128, (N + 127) / 128);
        k_gemm128<<<gg, 256, 0, stream>>>(A, W, feat, N, K, M);
    } else {
        dim3 gg(M / 64, (N + 127) / 128);
        k_gemm64<<<gg, 256, 0, stream>>>(A, W, feat, N, K, M);
    }

    int nh = N * H;
    k_el_er<<<(nh + 3) / 4, 256, 0, stream>>>(feat, al_, ar_, el, er, nh, H);
    k_node_ms<<<(nh + 255) / 256, 256, 0, stream>>>(row_start, src_sorted, el, er, m, s, N, H);

    int G = 256 / M;
    k_agg_csr<<<(N + G - 1) / G, 256, 0, stream>>>(row_start, src_sorted, feat, el, er, m, s,
                                                   b_, rstOut, H, N, do_relu ? 1 : 0);
}

extern "C" void kernel_launch(void* const* d_in, const int* in_sizes, int n_in,
                              void* d_out, int out_size, void* d_ws, size_t ws_size,
                              hipStream_t stream) {
    const float* features = (const float*)d_in[0];
    const int*   src = (const int*)d_in[1];
    const int*   dst = (const int*)d_in[2];
    const float* W1  = (const float*)d_in[3];
    const float* al1 = (const float*)d_in[4];
    const float* ar1 = (const float*)d_in[5];
    const float* b1  = (const float*)d_in[6];
    const float* W2  = (const float*)d_in[7];
    const float* al2 = (const float*)d_in[8];
    const float* ar2 = (const float*)d_in[9];
    const float* b2  = (const float*)d_in[10];
    const float* W3  = (const float*)d_in[11];
    const float* al3 = (const float*)d_in[12];
    const float* ar3 = (const float*)d_in[13];
    const float* b3  = (const float*)d_in[14];

    const int N = in_sizes[0] / 128;   // 50000
    const int E = in_sizes[1];         // 800000

    float* ws   = (float*)d_ws;
    size_t n256 = (size_t)N * 256;
    float* bufA = ws;                        // [N,256]
    float* bufB = bufA + n256;               // [N,256]
    float* el   = bufB + n256;               // [N,4]
    float* er   = el + (size_t)N * 4;        // [N,4]
    float* m    = er + (size_t)N * 4;        // [N,4]
    float* s    = m  + (size_t)N * 4;        // [N,4]
    int* cnt        = (int*)(s + (size_t)N * 4);   // [N]
    int* row_start  = cnt + N;                      // [N+1]
    int* cursor     = row_start + N + 1;            // [N]
    int* src_sorted = cursor + N;                   // [E]

    // ---- build dst-CSR (every call; deterministic, graph-capture safe) ----
    k_zero_int<<<(N + 255) / 256, 256, 0, stream>>>(cnt, N);
    k_hist<<<(E + 255) / 256, 256, 0, stream>>>(dst, cnt, E, N);
    k_scan<<<1, 1024, 0, stream>>>(cnt, row_start, cursor, N);
    k_scatter<<<(E + 255) / 256, 256, 0, stream>>>(src, dst, cursor, src_sorted, E, N);

    // layer 1: A=features[N,128] -> feat=bufB[N,256] -> rst=bufA[N,256] (+relu)
    run_layer(features, 128, W1, al1, ar1, b1, 4, bufB, bufA,
              el, er, m, s, row_start, src_sorted, N, E, true, stream);
    // layer 2
    run_layer(bufA, 256, W2, al2, ar2, b2, 4, bufB, bufA,
              el, er, m, s, row_start, src_sorted, N, E, true, stream);
    // layer 3: H=1; mean over 1 head is identity -> write straight to d_out
    run_layer(bufA, 256, W3, al3, ar3, b3, 1, bufB, (float*)d_out,
              el, er, m, s, row_start, src_sorted, N, E, false, stream);
}